// Round 14
// baseline (373.593 us; speedup 1.0000x reference)
//
#include <hip/hip_runtime.h>
#include <hip/hip_fp16.h>

#define IMG_W 2048
#define IMG_H 2048
#define HALF  10          // max_coc // 2
#define TILE  64          // 64x64 output tile
#define LW 84             // halo dim
#define NSTG (LW * LW)    // 7056

// GLOBAL weight LUT, TRANSPOSED layout: row = entry (0..49), 22 k-dwords per
// row, row stride 128 B (2 cache lines; entry is wave-uniform, only k varies
// per lane -> every wave load touches exactly 2 lines).
//   rows  0..21 : wy pairs; row a, k: pack2(wy(k,a-10), wy(k,a-11))
//   rows 22..35 : wx pairs;  row 22+h: pack2(wx(k,2h-13), wx(k,2h-12))
//   rows 36..49 : wx shifted; row 36+j: pack2(wx(k,2j-12), wx(k,2j-11))
#define LROWS 50
#define LRSB  128
#define LUT_BYTES (LROWS * LRSB)   // 6400
#define LMID  3200                 // mid-base bias so imm fits +-4095

__device__ __forceinline__ __half2 h2(uint u)  { union { uint a; __half2 b; } c; c.a = u; return c.b; }
__device__ __forceinline__ uint pack2(float a, float b) {
    return (uint)__half_as_ushort(__float2half(a)) |
           ((uint)__half_as_ushort(__float2half(b)) << 16);
}
// weight factors: w(k,oy,ox) = wyv(k,oy) * wxv(k,ox); norm folded into wy
__device__ __forceinline__ float wyv(int k, int oy) {
    int a = abs(oy), hk = k >> 1;
    if (a > hk) return 0.f;
    if (k <= 1) return 1.f;
    float kk = (float)(k * k);
    return expf(-(float)(oy * oy) * 18.f / kk) * 5.7295780f / kk;
}
__device__ __forceinline__ float wxv(int k, int ox) {
    int a = abs(ox), hk = k >> 1;
    if (a > hk) return 0.f;
    if (k <= 1) return 1.f;
    float kk = (float)(k * k);
    return expf(-(float)(ox * ox) * 18.f / kk);
}

// ---- tiny prologue kernel: build the transposed LUT in d_ws ----
__global__ void build_lut_kernel(uint* __restrict__ lutg)
{
    int i = blockIdx.x * blockDim.x + threadIdx.x;
    if (i >= LROWS * 22) return;
    int row = i / 22;
    int k   = i - row * 22;
    float lo = 0.f, hi = 0.f;
    if (row < 22) {                    // wy pair for source row a=row
        lo = wyv(k, row - 10);
        hi = wyv(k, row - 11);
    } else if (row < 36) {             // wx pair, pos (2h, 2h+1)
        int j = row - 22;
        lo = wxv(k, 2 * j - 13);
        hi = wxv(k, 2 * j - 12);
    } else {                           // shifted wx pair, pos (2j+1, 2j+2)
        int j = row - 36;
        lo = wxv(k, 2 * j - 12);
        hi = wxv(k, 2 * j - 11);
    }
    lutg[row * (LRSB / 4) + k] = pack2(lo, hi);
}

// VOP3P with explicit op_sel broadcasts (zero splat instructions):
#define FMA_LO(acc, px, wgt) \
    asm("v_pk_fma_f16 %0, %1, %2, %0 op_sel:[0,0,0] op_sel_hi:[0,1,1]" \
        : "+v"(acc) : "v"(px), "v"(wgt))
#define FMA_HI(acc, px, wgt) \
    asm("v_pk_fma_f16 %0, %1, %2, %0 op_sel:[1,0,0] op_sel_hi:[1,1,1]" \
        : "+v"(acc) : "v"(px), "v"(wgt))
#define MUL_WYLO(d, wx2, wy2) \
    asm("v_pk_mul_f16 %0, %1, %2 op_sel:[0,0] op_sel_hi:[1,0]" \
        : "=v"(d) : "v"(wx2), "v"(wy2))
#define MUL_WYHI(d, wx2, wy2) \
    asm("v_pk_mul_f16 %0, %1, %2 op_sel:[0,1] op_sel_hi:[1,1]" \
        : "=v"(d) : "v"(wx2), "v"(wy2))

__global__ __launch_bounds__(512, 4)
void defocus_glut_kernel(const float* __restrict__ img,
                         const int* __restrict__ ks,
                         const char* __restrict__ lutmid,   // lutg + LMID
                         float* __restrict__ out)
{
    __shared__ uint2 tile[NSTG];        // 56448 B (only LDS use)

    const int tid = threadIdx.x;
    const int X0 = blockIdx.x * TILE;
    const int Y0 = blockIdx.y * TILE;

    // ---- stage 84x84 halo tile, phase-major: {f16 r|g , u16 4k | f16 b} ----
    for (int i = tid; i < NSTG; i += 512) {
        int r = i / LW;
        int c = i - r * LW;
        int gy = Y0 - HALF + r;
        int gx = X0 - HALF + c;
        float fr = 0.f, fg = 0.f, fb = 0.f;
        uint koff = 0;
        if (gy >= 0 && gy < IMG_H && gx >= 0 && gx < IMG_W) {
            int p = gy * IMG_W + gx;
            fr = img[p * 3 + 0];
            fg = img[p * 3 + 1];
            fb = img[p * 3 + 2];
            koff = (uint)(ks[p] * 4);          // byte offset of k within a row
        }
        uint2 v;
        v.x = pack2(fr, fg);
        v.y = koff | ((uint)__half_as_ushort(__float2half(fb)) << 16);
        tile[r * LW + (c & 3) * 21 + (c >> 2)] = v;
    }
    __syncthreads();

    const int tx = tid & 15;       // 16 thread-cols
    const int ty = tid >> 4;       // 32 thread-rows
    const int colbase = tx * 4;
    const int rowbase = ty * 2;
    const int pxbase  = rowbase * LW + tx;

    // f16 pair accumulators: A32[r][ch]=(col3,col2), A10[r][ch]=(col1,col0)
    uint A32[2][3] = {{0,0,0},{0,0,0}}, A10[2][3] = {{0,0,0},{0,0,0}};
    float mc[2][4][3];              // f32 masters [r][col][ch]
    #pragma unroll
    for (int r = 0; r < 2; ++r)
        #pragma unroll
        for (int c = 0; c < 3; ++c)
            mc[r][0][c] = mc[r][1][c] = mc[r][2][c] = mc[r][3][c] = 0.f;

#define PIDX(b) (((b) & 3) * 21 + ((b) >> 2))
#define WROW(r) ((r) * LRSB - LMID)      // signed imm from mid-base, |.| <= 3200

#define PXG(buf, B0)                                   \
    { buf[0] = tile[pxrow + PIDX((B0) + 0)];           \
      buf[1] = tile[pxrow + PIDX((B0) + 1)];           \
      buf[2] = tile[pxrow + PIDX((B0) + 2)];           \
      buf[3] = tile[pxrow + PIDX((B0) + 3)];           \
      buf[4] = tile[pxrow + PIDX((B0) + 4)];           \
      buf[5] = tile[pxrow + PIDX((B0) + 5)];           \
      buf[6] = tile[pxrow + PIDX((B0) + 6)];           \
      buf[7] = tile[pxrow + PIDX((B0) + 7)]; }

    // weight fetch for one tap from the GLOBAL transposed LUT (L1-hot):
    // wave-uniform row (imm), per-lane k (voffset) -> 2 cache lines per load.
#define WLD1(q, pvv, aa, b)                                                        \
    { const char* wb = lutmid + ((pvv).y & 0xffffu);                               \
      (q).x = *(const uint*)(wb + WROW(aa));                                       \
      (q).y = (((b) & 1) == 0) ? *(const uint*)(wb + WROW(22 + ((b) >> 1)))        \
                               : *(const uint*)(wb + WROW(36 + (((b) - 1) >> 1))); \
      (q).z = (((b) & 1) == 0) ? *(const uint*)(wb + WROW(23 + ((b) >> 1)))        \
                               : *(const uint*)(wb + WROW(37 + (((b) - 1) >> 1))); }

#define WG(wv, buf, aa, B0)                 \
    { WLD1(wv[0], buf[0], aa, (B0) + 0);    \
      WLD1(wv[1], buf[1], aa, (B0) + 1);    \
      WLD1(wv[2], buf[2], aa, (B0) + 2);    \
      WLD1(wv[3], buf[3], aa, (B0) + 3);    \
      WLD1(wv[4], buf[4], aa, (B0) + 4);    \
      WLD1(wv[5], buf[5], aa, (B0) + 5);    \
      WLD1(wv[6], buf[6], aa, (B0) + 6);    \
      WLD1(wv[7], buf[7], aa, (B0) + 7); }

#define FMA1(pvv, q)                                                   \
    { uint W320, W100, W321, W101;                                     \
      MUL_WYLO(W320, (q).y, (q).x); MUL_WYLO(W100, (q).z, (q).x);      \
      MUL_WYHI(W321, (q).y, (q).x); MUL_WYHI(W101, (q).z, (q).x);      \
      FMA_LO(A32[0][0], (pvv).x, W320);                                \
      FMA_HI(A32[0][1], (pvv).x, W320);                                \
      FMA_HI(A32[0][2], (pvv).y, W320);                                \
      FMA_LO(A10[0][0], (pvv).x, W100);                                \
      FMA_HI(A10[0][1], (pvv).x, W100);                                \
      FMA_HI(A10[0][2], (pvv).y, W100);                                \
      FMA_LO(A32[1][0], (pvv).x, W321);                                \
      FMA_HI(A32[1][1], (pvv).x, W321);                                \
      FMA_HI(A32[1][2], (pvv).y, W321);                                \
      FMA_LO(A10[1][0], (pvv).x, W101);                                \
      FMA_HI(A10[1][1], (pvv).x, W101);                                \
      FMA_HI(A10[1][2], (pvv).y, W101); }

#define FMAG(buf, wv)          \
    { FMA1(buf[0], wv[0]);     \
      FMA1(buf[1], wv[1]);     \
      FMA1(buf[2], wv[2]);     \
      FMA1(buf[3], wv[3]);     \
      FMA1(buf[4], wv[4]);     \
      FMA1(buf[5], wv[5]);     \
      FMA1(buf[6], wv[6]);     \
      FMA1(buf[7], wv[7]); }

    // One source row: 3 groups of 8 taps, px prefetched ahead, batched weights
#define ROW(aa)                            \
    { const int pxrow = pxbase + (aa) * LW;\
      uint2 p0[8], p1[8];                  \
      uint3 wv[8];                         \
      PXG(p0, 0);                          \
      PXG(p1, 8);                          \
      WG(wv, p0, (aa), 0);                 \
      FMAG(p0, wv);                        \
      PXG(p0, 16);                         \
      WG(wv, p1, (aa), 8);                 \
      FMAG(p1, wv);                        \
      WG(wv, p0, (aa), 16);                \
      FMAG(p0, wv); }

#define FLUSH()                                                        \
    { _Pragma("unroll")                                                \
      for (int r = 0; r < 2; ++r) {                                    \
          _Pragma("unroll")                                            \
          for (int c = 0; c < 3; ++c) {                                \
              float2 f3 = __half22float2(h2(A32[r][c]));               \
              float2 f1 = __half22float2(h2(A10[r][c]));               \
              mc[r][3][c] += f3.x; mc[r][2][c] += f3.y;                \
              mc[r][1][c] += f1.x; mc[r][0][c] += f1.y;                \
              A32[r][c] = 0; A10[r][c] = 0;                            \
          }                                                            \
      } }

    // 22 source rows, flush f16 partials (<=48 taps) every 2 rows
    #pragma unroll 1
    for (int ap = 0; ap < 11; ++ap) {
        ROW(2 * ap);
        ROW(2 * ap + 1);
        FLUSH();
    }

    // ---- store ----
    #pragma unroll
    for (int r = 0; r < 2; ++r) {
        int gy = Y0 + rowbase + r;
        #pragma unroll
        for (int m = 0; m < 4; ++m) {
            int gx = X0 + colbase + m;
            int o = (gy * IMG_W + gx) * 3;
            out[o + 0] = mc[r][m][0];
            out[o + 1] = mc[r][m][1];
            out[o + 2] = mc[r][m][2];
        }
    }
#undef ROW
#undef FLUSH
#undef PXG
#undef WG
#undef FMAG
#undef FMA1
#undef WLD1
#undef WROW
#undef PIDX
}

extern "C" void kernel_launch(void* const* d_in, const int* in_sizes, int n_in,
                              void* d_out, int out_size, void* d_ws, size_t ws_size,
                              hipStream_t stream) {
    const float* img = (const float*)d_in[0];
    const int*   ks  = (const int*)d_in[1];
    float* out = (float*)d_out;
    uint*  lutg = (uint*)d_ws;                       // 6400 B in workspace

    build_lut_kernel<<<(LROWS * 22 + 255) / 256, 256, 0, stream>>>(lutg);

    dim3 grid(IMG_W / TILE, IMG_H / TILE);           // 32 x 32
    dim3 block(512);
    defocus_glut_kernel<<<grid, block, 0, stream>>>(
        img, ks, (const char*)d_ws + LMID, out);
}

// Round 15
// 173.872 us; speedup vs baseline: 2.1487x; 2.1487x over previous
//
#include <hip/hip_runtime.h>
#include <hip/hip_fp16.h>

#define IMG_W 2048
#define IMG_H 2048
#define HALF  10          // max_coc // 2
#define TILE  64          // 64x64 output tile
#define LW 84             // halo dim
#define NSTG (LW * LW)    // 7056

// Separable LUT, one 74-dword plane per k (stride = 2*37: 8B-aligned planes,
// and 37 odd -> b64 bank-pair slot (37k+..) mod 16 injective-ish over k):
//   dwords  0..21 : wy pairs; entry a = pack2(wy(a-10), wy(a-11)) (lo->r0, hi->r1)
//   dwords 22..69 : wx quads; entry b (0..23) at dwords 22+2b:
//                   d0 = pack2(wx(b-13), wx(b-12))   (cols 3,2)
//                   d1 = pack2(wx(b-11), wx(b-10))   (cols 1,0)
//   dwords 70..73 : pad
#define L_KSD 74
#define L_KSB 296              // byte plane stride (k*296 <= 6216, fits u16)
#define L_NDW (22 * L_KSD)     // 1628 dwords = 6512 B

__device__ __forceinline__ __half2 h2(uint u)  { union { uint a; __half2 b; } c; c.a = u; return c.b; }
__device__ __forceinline__ uint pack2(float a, float b) {
    return (uint)__half_as_ushort(__float2half(a)) |
           ((uint)__half_as_ushort(__float2half(b)) << 16);
}
// weight factors: w(k,oy,ox) = wyv(k,oy) * wxv(k,ox); norm folded into wy
__device__ __forceinline__ float wyv(int k, int oy) {
    int a = abs(oy), hk = k >> 1;
    if (a > hk) return 0.f;
    if (k <= 1) return 1.f;
    float kk = (float)(k * k);
    return expf(-(float)(oy * oy) * 18.f / kk) * 5.7295780f / kk;
}
__device__ __forceinline__ float wxv(int k, int ox) {
    int a = abs(ox), hk = k >> 1;
    if (a > hk) return 0.f;
    if (k <= 1) return 1.f;
    float kk = (float)(k * k);
    return expf(-(float)(ox * ox) * 18.f / kk);
}

// VOP3P with explicit op_sel broadcasts (zero splat instructions):
#define FMA_LO(acc, px, wgt) \
    asm("v_pk_fma_f16 %0, %1, %2, %0 op_sel:[0,0,0] op_sel_hi:[0,1,1]" \
        : "+v"(acc) : "v"(px), "v"(wgt))
#define FMA_HI(acc, px, wgt) \
    asm("v_pk_fma_f16 %0, %1, %2, %0 op_sel:[1,0,0] op_sel_hi:[1,1,1]" \
        : "+v"(acc) : "v"(px), "v"(wgt))
#define MUL_WYLO(d, wx2, wy2) \
    asm("v_pk_mul_f16 %0, %1, %2 op_sel:[0,0] op_sel_hi:[1,0]" \
        : "=v"(d) : "v"(wx2), "v"(wy2))
#define MUL_WYHI(d, wx2, wy2) \
    asm("v_pk_mul_f16 %0, %1, %2 op_sel:[0,1] op_sel_hi:[1,1]" \
        : "=v"(d) : "v"(wx2), "v"(wy2))

__global__ __launch_bounds__(512, 4)
void defocus_b64_kernel(const float* __restrict__ img,
                        const int* __restrict__ ks,
                        float* __restrict__ out)
{
    __shared__ __align__(16) uint  lutw[L_NDW];   // 6512 B
    __shared__ __align__(16) uint2 tile[NSTG];    // 56448 B  (total ~62.9 KB)

    const int tid = threadIdx.x;
    const int X0 = blockIdx.x * TILE;
    const int Y0 = blockIdx.y * TILE;

    // ---- build separable LUT ----
    for (int i = tid; i < L_NDW; i += 512) {
        int k = i / L_KSD;
        int d = i - k * L_KSD;
        float lo = 0.f, hi = 0.f;
        if (d < 22) {                       // wy pair for source row a=d
            lo = wyv(k, d - 10);
            hi = wyv(k, d - 11);
        } else if (d < 70) {                // wx quad entry b, half q
            int b = (d - 22) >> 1;
            int q = (d - 22) & 1;
            lo = wxv(k, b - 13 + 2 * q);
            hi = wxv(k, b - 12 + 2 * q);
        }
        lutw[i] = pack2(lo, hi);
    }

    // ---- stage 84x84 halo tile, phase-major: {f16 r|g , u16 koffB=k*296 | f16 b} ----
    for (int i = tid; i < NSTG; i += 512) {
        int r = i / LW;
        int c = i - r * LW;
        int gy = Y0 - HALF + r;
        int gx = X0 - HALF + c;
        float fr = 0.f, fg = 0.f, fb = 0.f;
        uint koffB = 0;
        if (gy >= 0 && gy < IMG_H && gx >= 0 && gx < IMG_W) {
            int p = gy * IMG_W + gx;
            fr = img[p * 3 + 0];
            fg = img[p * 3 + 1];
            fb = img[p * 3 + 2];
            koffB = (uint)(ks[p] * L_KSB);
        }
        uint2 v;
        v.x = pack2(fr, fg);
        v.y = koffB | ((uint)__half_as_ushort(__float2half(fb)) << 16);
        tile[r * LW + (c & 3) * 21 + (c >> 2)] = v;
    }
    __syncthreads();

    const int tx = tid & 15;       // 16 thread-cols
    const int ty = tid >> 4;       // 32 thread-rows
    const int colbase = tx * 4;
    const int rowbase = ty * 2;
    const int pxbase  = rowbase * LW + tx;

    // f16 pair accumulators: A32[r][ch]=(col3,col2), A10[r][ch]=(col1,col0)
    uint A32[2][3] = {{0,0,0},{0,0,0}}, A10[2][3] = {{0,0,0},{0,0,0}};
    float mc[2][4][3];              // f32 masters [r][col][ch]
    #pragma unroll
    for (int r = 0; r < 2; ++r)
        #pragma unroll
        for (int c = 0; c < 3; ++c)
            mc[r][0][c] = mc[r][1][c] = mc[r][2][c] = mc[r][3][c] = 0.f;

#define PIDX(b) (((b) & 3) * 21 + ((b) >> 2))

#define PXG(buf, B0)                                   \
    { buf[0] = tile[pxrow + PIDX((B0) + 0)];           \
      buf[1] = tile[pxrow + PIDX((B0) + 1)];           \
      buf[2] = tile[pxrow + PIDX((B0) + 2)];           \
      buf[3] = tile[pxrow + PIDX((B0) + 3)];           \
      buf[4] = tile[pxrow + PIDX((B0) + 4)];           \
      buf[5] = tile[pxrow + PIDX((B0) + 5)];           \
      buf[6] = tile[pxrow + PIDX((B0) + 6)];           \
      buf[7] = tile[pxrow + PIDX((B0) + 7)]; }

    // weight fetch: 1 b32 (wy) + 1 aligned b64 (wx quad), both compile-time offsets
#define WLD1(q, pvv, aa, b)                                                   \
    { const uint* wp = (const uint*)((const char*)lutw + ((pvv).y & 0xffffu));\
      (q).x = wp[(aa)];                                                       \
      uint2 wx2_ = *(const uint2*)(wp + 22 + 2 * (b));                        \
      (q).y = wx2_.x;                                                         \
      (q).z = wx2_.y; }

#define WG(wv, buf, aa, B0)                 \
    { WLD1(wv[0], buf[0], aa, (B0) + 0);    \
      WLD1(wv[1], buf[1], aa, (B0) + 1);    \
      WLD1(wv[2], buf[2], aa, (B0) + 2);    \
      WLD1(wv[3], buf[3], aa, (B0) + 3);    \
      WLD1(wv[4], buf[4], aa, (B0) + 4);    \
      WLD1(wv[5], buf[5], aa, (B0) + 5);    \
      WLD1(wv[6], buf[6], aa, (B0) + 6);    \
      WLD1(wv[7], buf[7], aa, (B0) + 7); }

#define FMA1(pvv, q)                                                   \
    { uint W320, W100, W321, W101;                                     \
      MUL_WYLO(W320, (q).y, (q).x); MUL_WYLO(W100, (q).z, (q).x);      \
      MUL_WYHI(W321, (q).y, (q).x); MUL_WYHI(W101, (q).z, (q).x);      \
      FMA_LO(A32[0][0], (pvv).x, W320);                                \
      FMA_HI(A32[0][1], (pvv).x, W320);                                \
      FMA_HI(A32[0][2], (pvv).y, W320);                                \
      FMA_LO(A10[0][0], (pvv).x, W100);                                \
      FMA_HI(A10[0][1], (pvv).x, W100);                                \
      FMA_HI(A10[0][2], (pvv).y, W100);                                \
      FMA_LO(A32[1][0], (pvv).x, W321);                                \
      FMA_HI(A32[1][1], (pvv).x, W321);                                \
      FMA_HI(A32[1][2], (pvv).y, W321);                                \
      FMA_LO(A10[1][0], (pvv).x, W101);                                \
      FMA_HI(A10[1][1], (pvv).x, W101);                                \
      FMA_HI(A10[1][2], (pvv).y, W101); }

#define FMAG(buf, wv)          \
    { FMA1(buf[0], wv[0]);     \
      FMA1(buf[1], wv[1]);     \
      FMA1(buf[2], wv[2]);     \
      FMA1(buf[3], wv[3]);     \
      FMA1(buf[4], wv[4]);     \
      FMA1(buf[5], wv[5]);     \
      FMA1(buf[6], wv[6]);     \
      FMA1(buf[7], wv[7]); }

    // One source row: 3 groups of 8 taps, px prefetched ahead, batched weights
#define ROW(aa)                            \
    { const int pxrow = pxbase + (aa) * LW;\
      uint2 p0[8], p1[8];                  \
      uint3 wv[8];                         \
      PXG(p0, 0);                          \
      PXG(p1, 8);                          \
      WG(wv, p0, (aa), 0);                 \
      FMAG(p0, wv);                        \
      PXG(p0, 16);                         \
      WG(wv, p1, (aa), 8);                 \
      FMAG(p1, wv);                        \
      WG(wv, p0, (aa), 16);                \
      FMAG(p0, wv); }

#define FLUSH()                                                        \
    { _Pragma("unroll")                                                \
      for (int r = 0; r < 2; ++r) {                                    \
          _Pragma("unroll")                                            \
          for (int c = 0; c < 3; ++c) {                                \
              float2 f3 = __half22float2(h2(A32[r][c]));               \
              float2 f1 = __half22float2(h2(A10[r][c]));               \
              mc[r][3][c] += f3.x; mc[r][2][c] += f3.y;                \
              mc[r][1][c] += f1.x; mc[r][0][c] += f1.y;                \
              A32[r][c] = 0; A10[r][c] = 0;                            \
          }                                                            \
      } }

    // 22 source rows, flush f16 partials (<=48 taps) every 2 rows
    #pragma unroll 1
    for (int ap = 0; ap < 11; ++ap) {
        ROW(2 * ap);
        ROW(2 * ap + 1);
        FLUSH();
    }

    // ---- store ----
    #pragma unroll
    for (int r = 0; r < 2; ++r) {
        int gy = Y0 + rowbase + r;
        #pragma unroll
        for (int m = 0; m < 4; ++m) {
            int gx = X0 + colbase + m;
            int o = (gy * IMG_W + gx) * 3;
            out[o + 0] = mc[r][m][0];
            out[o + 1] = mc[r][m][1];
            out[o + 2] = mc[r][m][2];
        }
    }
#undef ROW
#undef FLUSH
#undef PXG
#undef WG
#undef FMAG
#undef FMA1
#undef WLD1
#undef PIDX
}

extern "C" void kernel_launch(void* const* d_in, const int* in_sizes, int n_in,
                              void* d_out, int out_size, void* d_ws, size_t ws_size,
                              hipStream_t stream) {
    const float* img = (const float*)d_in[0];
    const int*   ks  = (const int*)d_in[1];
    float* out = (float*)d_out;

    dim3 grid(IMG_W / TILE, IMG_H / TILE);   // 32 x 32
    dim3 block(512);
    defocus_b64_kernel<<<grid, block, 0, stream>>>(img, ks, out);
}